// Round 5
// baseline (335.930 us; speedup 1.0000x reference)
//
#include <hip/hip_runtime.h>

#define BB 128
#define TT 512
#define CC 128

typedef short short8 __attribute__((ext_vector_type(8)));
typedef float f32x4  __attribute__((ext_vector_type(4)));

__device__ __forceinline__ unsigned pk_trunc(float a, float b) {
    // lo16 = trunc-bf16(a), hi16 = trunc-bf16(b); single v_perm
    return __builtin_amdgcn_perm(__float_as_uint(a), __float_as_uint(b), 0x03020706u);
}
__device__ __forceinline__ unsigned short f2bf(float f) {   // RNE (one-time E setup)
    unsigned u = __float_as_uint(f);
    u += 0x7fffu + ((u >> 16) & 1u);
    return (unsigned short)(u >> 16);
}
__device__ __forceinline__ float lo16f(unsigned u) { return __uint_as_float(u << 16); }
__device__ __forceinline__ float hi16f(unsigned u) { return __uint_as_float(u & 0xffff0000u); }

// ---------------------------------------------------------------------------
// Prep: ws[id] = exp(y_pred * mask) gathered into the scan's B-layout order.
// id = ((g*512 + t)*8 + c)*64 + lane ; float4 per thread.
// ---------------------------------------------------------------------------
__global__ __launch_bounds__(256) void crf_prep(
    const float* __restrict__ yp, const float* __restrict__ mask,
    float4* __restrict__ ws)
{
    const int id   = blockIdx.x * 256 + threadIdx.x;
    const int lane = id & 63;
    const int c    = (id >> 6) & 7;
    const int t    = (id >> 9) & 511;
    const int g    = id >> 18;
    const int b    = g * 16 + (lane & 15);
    const int q    = (lane >> 4);
    const int j0   = ((c >> 1) * 32) + q * 8 + ((c & 1) * 4);
    const float4 v = *(const float4*)(yp + ((size_t)b * TT + t) * CC + j0);
    const float m  = mask[b * TT + t];
    float4 r;
    r.x = __expf(v.x * m); r.y = __expf(v.y * m);
    r.z = __expf(v.z * m); r.w = __expf(v.w * m);
    ws[id] = r;
}

// ---------------------------------------------------------------------------
// Fused: blocks 0..7 = barrier-free in-register MFMA scan (16 batches/wave),
// depth-4 prefetch ring on e(t); blocks 8..1031 = real-path score waves.
// ---------------------------------------------------------------------------
template<bool USE_WS>
__global__ __launch_bounds__(64, 1) void crf_fused(
    const float* __restrict__ y_true, const float* __restrict__ y_pred,
    const float* __restrict__ mask, const float* __restrict__ trans,
    const float4* __restrict__ ws, float* __restrict__ out)
{
    const int lane = threadIdx.x;

    if (blockIdx.x >= 8) {
        // ===================== real path (R3/R4-verified logic) =============
        const int rbw = blockIdx.x - 8;
        const int rb  = rbw >> 3;
        const int w   = rbw & 7;
        const int ts  = w * 64;
        const int te  = min(ts + 64, TT - 1);
        const float* yt_b = y_true + (size_t)rb * TT * CC;
        const float* yp_b = y_pred + (size_t)rb * TT * CC;
        const float* m_b  = mask + (size_t)rb * TT;

        float em = 0.f, tr = 0.f;
        int lprev = 0; float mprev = 0.f;
        const float* ytr = yt_b + ts * CC;
        const float* ypr = yp_b + ts * CC;
        float cyt0 = ytr[lane], cyt1 = ytr[lane + 64];
        float cyp0 = ypr[lane], cyp1 = ypr[lane + 64];
        float cm = m_b[ts];
        for (int t = ts; t <= te; ++t) {
            float nyt0 = 0.f, nyt1 = 0.f, nyp0 = 0.f, nyp1 = 0.f, nm = 0.f;
            if (t < te) {
                const float* ytn = yt_b + (t + 1) * CC;
                const float* ypn = yp_b + (t + 1) * CC;
                nyt0 = ytn[lane]; nyt1 = ytn[lane + 64];
                nyp0 = ypn[lane]; nyp1 = ypn[lane + 64];
                nm = m_b[t + 1];
            }
            unsigned long long b0 = __ballot(cyt0 > 0.5f);
            unsigned long long b1 = __ballot(cyt1 > 0.5f);
            int l = b0 ? (__ffsll(b0) - 1) : (64 + __ffsll(b1) - 1);
            float v0 = __shfl(cyp0, l & 63);
            float v1 = __shfl(cyp1, l & 63);
            float v  = (l < 64) ? v0 : v1;
            if (lane == 0) {
                if (t < ts + 64) em += cm * cm * v;
                if (t > ts)      tr += mprev * cm * trans[lprev * CC + l];
            }
            lprev = l; mprev = cm;
            cyt0 = nyt0; cyt1 = nyt1; cyp0 = nyp0; cyp1 = nyp1; cm = nm;
        }
        if (lane == 0) atomicAdd(&out[rb], -(em + tr));
        return;
    }

    // ========================= in-register scan =========================
    const int g  = blockIdx.x;
    const int bq = lane & 15;
    const int q  = lane >> 4;

    // A-frags: Af[nt][kt] = E^T tile with row perm sigma (R4-verified).
    short8 Af[8][4];
    #pragma unroll
    for (int nt = 0; nt < 8; ++nt) {
        const int j = 32 * (nt & 3) + 8 * (bq >> 2) + 4 * (nt >> 2) + (bq & 3);
        #pragma unroll
        for (int kt = 0; kt < 4; ++kt) {
            #pragma unroll
            for (int e = 0; e < 8; ++e) {
                const int i = kt * 32 + q * 8 + e;
                Af[nt][kt][e] = (short)f2bf(__expf(trans[i * CC + j]));
            }
        }
    }

    const float4* wsg = ws + (size_t)g * (TT * 8 * 64) + lane;
    const float* yaddr[8];
    {
        const float* ybase = y_pred + (size_t)(g * 16 + bq) * TT * CC;
        #pragma unroll
        for (int c = 0; c < 8; ++c)
            yaddr[c] = ybase + ((c >> 1) * 32 + q * 8 + (c & 1) * 4);
    }
    const float* mrow = mask + (size_t)(g * 16 + bq) * TT;

    float4 eb[4][8];          // depth-4 prefetch ring, slot = t & 3
    float  ms[4];

    auto loadE = [&](int t, int slot) {
        const float4* p = USE_WS ? (wsg + (size_t)t * 512) : nullptr;
        #pragma unroll
        for (int c = 0; c < 8; ++c)
            eb[slot][c] = USE_WS ? p[c * 64]
                                 : *(const float4*)(yaddr[c] + (size_t)t * CC);
        ms[slot] = mrow[t];
    };
    auto getE = [&](const float4& raw, float mv) -> float4 {
        if (USE_WS) return raw;
        float4 r;
        r.x = __expf(raw.x * mv); r.y = __expf(raw.y * mv);
        r.z = __expf(raw.z * mv); r.w = __expf(raw.w * mv);
        return r;
    };

    float pend = 1.f, lacc = 0.f;
    unsigned ps[16];           // packed bf16 state = next-step B-fragments

    // t=0 init: S0 = e(0)  (use slot 0 transiently)
    loadE(0, 0);
    #pragma unroll
    for (int c = 0; c < 8; ++c) {
        float4 e0 = getE(eb[0][c], ms[0]);
        const int kt = c >> 1, h = c & 1;
        ps[kt * 4 + 2 * h + 0] = pk_trunc(e0.x, e0.y);
        ps[kt * 4 + 2 * h + 1] = pk_trunc(e0.z, e0.w);
    }
    loadE(1, 1); loadE(2, 2); loadE(3, 3);

#define DOSTEP(T, SLOT, AP, RN, LOAD)                                             \
    do {                                                                          \
        if (LOAD) loadE((T) + 3, ((T) + 3) & 3);      /* issue early, use in 3 */ \
        short8 Bf[4];                                                             \
        _Pragma("unroll")                                                         \
        for (int kt = 0; kt < 4; ++kt) {                                          \
            union { unsigned u[4]; short8 s; } bu;                                \
            bu.u[0] = ps[kt * 4 + 0]; bu.u[1] = ps[kt * 4 + 1];                   \
            bu.u[2] = ps[kt * 4 + 2]; bu.u[3] = ps[kt * 4 + 3];                   \
            Bf[kt] = bu.s;                                                        \
        }                                                                         \
        f32x4 acc[8];                                                             \
        _Pragma("unroll")                                                         \
        for (int nt = 0; nt < 8; ++nt) {                                          \
            f32x4 a = {0.f, 0.f, 0.f, 0.f};                                       \
            a = __builtin_amdgcn_mfma_f32_16x16x32_bf16(Af[nt][0], Bf[0], a, 0, 0, 0); \
            a = __builtin_amdgcn_mfma_f32_16x16x32_bf16(Af[nt][1], Bf[1], a, 0, 0, 0); \
            a = __builtin_amdgcn_mfma_f32_16x16x32_bf16(Af[nt][2], Bf[2], a, 0, 0, 0); \
            a = __builtin_amdgcn_mfma_f32_16x16x32_bf16(Af[nt][3], Bf[3], a, 0, 0, 0); \
            acc[nt] = a;                                                          \
        }                                                                         \
        const float mv = ms[SLOT];                                                \
        float val[8][4];                                                          \
        _Pragma("unroll")                                                         \
        for (int nt = 0; nt < 8; ++nt) {                                          \
            const int c = 2 * (nt & 3) + (nt >> 2);                               \
            float4 e = getE(eb[SLOT][c], mv);                                     \
            val[nt][0] = acc[nt][0] * e.x; val[nt][1] = acc[nt][1] * e.y;         \
            val[nt][2] = acc[nt][2] * e.z; val[nt][3] = acc[nt][3] * e.w;         \
            if (AP) {                                                             \
                val[nt][0] *= pend; val[nt][1] *= pend;                           \
                val[nt][2] *= pend; val[nt][3] *= pend;                           \
            }                                                                     \
        }                                                                         \
        unsigned nps[16];                                                         \
        _Pragma("unroll")                                                         \
        for (int nt = 0; nt < 8; ++nt) {                                          \
            const int kt = nt & 3, h = nt >> 2;                                   \
            nps[kt * 4 + 2 * h + 0] = pk_trunc(val[nt][0], val[nt][1]);           \
            nps[kt * 4 + 2 * h + 1] = pk_trunc(val[nt][2], val[nt][3]);           \
        }                                                                         \
        if (__ballot(mv <= 0.f)) {                                                \
            _Pragma("unroll")                                                     \
            for (int p = 0; p < 16; ++p) {                                        \
                unsigned kept = pk_trunc(lo16f(ps[p]) * pend, hi16f(ps[p]) * pend); \
                nps[p] = (mv <= 0.f) ? kept : nps[p];                             \
            }                                                                     \
        }                                                                         \
        _Pragma("unroll")                                                         \
        for (int p = 0; p < 16; ++p) ps[p] = nps[p];                              \
        if (AP) pend = 1.f;                                                       \
        if (RN) {                                                                 \
            float s  = lo16f(ps[0]);                                              \
            float bc = __shfl(s, bq, 64);                                         \
            pend = __builtin_amdgcn_rcpf(bc);                                     \
            lacc += __logf(bc);                                                   \
        }                                                                         \
    } while (0)

    // hot loop: t = 1 .. 504, loads always valid (t+3 <= 507)
    for (int k = 0; k < 126; ++k) {
        const int t0 = 4 * k + 1;
        DOSTEP(t0,     1, true,  false, true);
        DOSTEP(t0 + 1, 2, false, false, true);
        DOSTEP(t0 + 2, 3, false, false, true);
        DOSTEP(t0 + 3, 0, false, true,  true);
    }
    // peel: 505..510 (loads for 508..511 valid; none beyond)
    DOSTEP(505, 1, true,  false, true);
    DOSTEP(506, 2, false, false, true);
    DOSTEP(507, 3, false, false, true);
    DOSTEP(508, 0, false, true,  true);
    DOSTEP(509, 1, true,  false, false);
    DOSTEP(510, 2, false, false, false);

    // -------- final step t = 511 (slot 3): sum instead of pack --------
    {
        short8 Bf[4];
        #pragma unroll
        for (int kt = 0; kt < 4; ++kt) {
            union { unsigned u[4]; short8 s; } bu;
            bu.u[0] = ps[kt * 4 + 0]; bu.u[1] = ps[kt * 4 + 1];
            bu.u[2] = ps[kt * 4 + 2]; bu.u[3] = ps[kt * 4 + 3];
            Bf[kt] = bu.s;
        }
        float ssum = 0.f;
        const float mv = ms[3];
        #pragma unroll
        for (int nt = 0; nt < 8; ++nt) {
            f32x4 a = {0.f, 0.f, 0.f, 0.f};
            a = __builtin_amdgcn_mfma_f32_16x16x32_bf16(Af[nt][0], Bf[0], a, 0, 0, 0);
            a = __builtin_amdgcn_mfma_f32_16x16x32_bf16(Af[nt][1], Bf[1], a, 0, 0, 0);
            a = __builtin_amdgcn_mfma_f32_16x16x32_bf16(Af[nt][2], Bf[2], a, 0, 0, 0);
            a = __builtin_amdgcn_mfma_f32_16x16x32_bf16(Af[nt][3], Bf[3], a, 0, 0, 0);
            const int c = 2 * (nt & 3) + (nt >> 2);
            float4 e = getE(eb[3][c], mv);
            ssum += a[0] * e.x + a[1] * e.y + a[2] * e.z + a[3] * e.w;
        }
        if (__ballot(mv <= 0.f)) {
            float os = 0.f;
            #pragma unroll
            for (int p = 0; p < 16; ++p) os += lo16f(ps[p]) + hi16f(ps[p]);
            ssum = (mv <= 0.f) ? os : ssum;   // pend == 1 here (511 % 4 == 3)
        }
        ssum += __shfl_xor(ssum, 16, 64);
        ssum += __shfl_xor(ssum, 32, 64);
        if (lane < 16) atomicAdd(&out[g * 16 + lane], __logf(ssum) + lacc);
    }
#undef DOSTEP
}

// ---------------------------------------------------------------------------
extern "C" void kernel_launch(void* const* d_in, const int* in_sizes, int n_in,
                              void* d_out, int out_size, void* d_ws, size_t ws_size,
                              hipStream_t stream) {
    (void)in_sizes; (void)n_in; (void)out_size;
    const float* y_true = (const float*)d_in[0];
    const float* y_pred = (const float*)d_in[1];
    const float* mask   = (const float*)d_in[2];
    const float* trans  = (const float*)d_in[3];
    float* out = (float*)d_out;

    const size_t need = (size_t)BB * TT * CC * sizeof(float);   // 32 MB
    hipMemsetAsync(out, 0, BB * sizeof(float), stream);
    if (ws_size >= need) {
        crf_prep<<<8192, 256, 0, stream>>>(y_pred, mask, (float4*)d_ws);
        crf_fused<true><<<8 + BB * 8, 64, 0, stream>>>(
            y_true, y_pred, mask, trans, (const float4*)d_ws, out);
    } else {
        crf_fused<false><<<8 + BB * 8, 64, 0, stream>>>(
            y_true, y_pred, mask, trans, (const float4*)d_ws, out);
    }
}